// Round 3
// baseline (259.606 us; speedup 1.0000x reference)
//
#include <hip/hip_runtime.h>

#define NH 16
#define HS 64
#define HID 1024
#define SEQ 2048
#define BB 4
#define MR (BB*SEQ)   // 8192 rows
#define KD 1024

typedef __bf16 bf16;
typedef __attribute__((ext_vector_type(8))) __bf16 bf16x8;
typedef __attribute__((ext_vector_type(4))) __bf16 bf16x4;
typedef __attribute__((ext_vector_type(4))) float f32x4;
typedef __attribute__((ext_vector_type(4))) float f4;

typedef __attribute__((address_space(3))) unsigned int as3u;
typedef __attribute__((address_space(1))) unsigned int as1u;

__device__ __forceinline__ void gl_lds16(const void* g, void* l) {
  __builtin_amdgcn_global_load_lds((const as1u*)g, (as3u*)l, 16, 0, 0);
}

__device__ __forceinline__ f32x4 mfma16(bf16x8 a, bf16x8 b, f32x4 c) {
  return __builtin_amdgcn_mfma_f32_16x16x32_bf16(a, b, c, 0, 0, 0);
}

// ---------------- fp32 -> bf16 conversion ----------------
__global__ __launch_bounds__(256) void k_cvt(const float* __restrict__ in,
                                             bf16* __restrict__ out, int n4) {
  int i = blockIdx.x * 256 + threadIdx.x;
  if (i >= n4) return;
  f4 v = reinterpret_cast<const f4*>(in)[i];
  bf16x4 h;
  h[0] = (bf16)v[0]; h[1] = (bf16)v[1]; h[2] = (bf16)v[2]; h[3] = (bf16)v[3];
  reinterpret_cast<bf16x4*>(out)[i] = h;
}

// 4 weight matrices in one launch (blockIdx.y selects)
__global__ __launch_bounds__(256) void k_cvt4(const float* __restrict__ w0, const float* __restrict__ w1,
                                              const float* __restrict__ w2, const float* __restrict__ w3,
                                              bf16* __restrict__ o0, bf16* __restrict__ o1,
                                              bf16* __restrict__ o2, bf16* __restrict__ o3, int n4) {
  int i = blockIdx.x * 256 + threadIdx.x;
  if (i >= n4) return;
  const float* in = (blockIdx.y == 0) ? w0 : (blockIdx.y == 1) ? w1 : (blockIdx.y == 2) ? w2 : w3;
  bf16* out = (blockIdx.y == 0) ? o0 : (blockIdx.y == 1) ? o1 : (blockIdx.y == 2) ? o2 : o3;
  f4 v = reinterpret_cast<const f4*>(in)[i];
  bf16x4 h;
  h[0] = (bf16)v[0]; h[1] = (bf16)v[1]; h[2] = (bf16)v[2]; h[3] = (bf16)v[3];
  reinterpret_cast<bf16x4*>(out)[i] = h;
}

// ---------------- NT GEMM: C[m,n] = sum_k A[m,k]*W[n,k] ----------------
// MODE 0: bf16 out, head-split [b][h][s][d], (acc+bias)*scale
// MODE 1: f32 out, flat [m][n]
// MODE 2: bf16 out, head-split TRANSPOSED [b][h][d][s]  (for V)
template<int MODE>
__global__ __launch_bounds__(256) void k_gemm(const bf16* __restrict__ A,
                                              const bf16* __restrict__ Bw,
                                              const float* __restrict__ bias,
                                              void* __restrict__ outp, float scale) {
  __shared__ __align__(16) bf16 As[128*32];
  __shared__ __align__(16) bf16 Bs[128*32];
  const int tid = threadIdx.x;
  const int l = tid & 63, w = tid >> 6;
  const int m0 = blockIdx.x * 128, n0 = blockIdx.y * 128;
  const int wr = w >> 1, wc = w & 1;

  f32x4 acc[4][4] = {};

  const int srow = 32*w + (l >> 2);
  const int scol = (l & 3) * 8;
  const bf16* Asrc = A  + (size_t)(m0 + srow) * KD + scol;
  const bf16* Bsrc = Bw + (size_t)(n0 + srow) * KD + scol;
  char* AsBase = (char*)As + (size_t)(w*2) * 1024;
  char* BsBase = (char*)Bs + (size_t)(w*2) * 1024;

  for (int kt = 0; kt < KD; kt += 32) {
    gl_lds16(Asrc + kt,                 AsBase);
    gl_lds16(Asrc + kt + (size_t)16*KD, AsBase + 1024);
    gl_lds16(Bsrc + kt,                 BsBase);
    gl_lds16(Bsrc + kt + (size_t)16*KD, BsBase + 1024);
    __syncthreads();

    bf16x8 af[4], bv[4];
    const int koff = (l >> 4) * 8;
    #pragma unroll
    for (int mf = 0; mf < 4; mf++)
      af[mf] = *reinterpret_cast<const bf16x8*>(&As[(wr*64 + mf*16 + (l & 15))*32 + koff]);
    #pragma unroll
    for (int nf = 0; nf < 4; nf++)
      bv[nf] = *reinterpret_cast<const bf16x8*>(&Bs[(wc*64 + nf*16 + (l & 15))*32 + koff]);
    #pragma unroll
    for (int mf = 0; mf < 4; mf++)
      #pragma unroll
      for (int nf = 0; nf < 4; nf++)
        acc[mf][nf] = mfma16(af[mf], bv[nf], acc[mf][nf]);
    __syncthreads();
  }

  #pragma unroll
  for (int mf = 0; mf < 4; mf++) {
    #pragma unroll
    for (int nf = 0; nf < 4; nf++) {
      const int n = n0 + wc*64 + nf*16 + (l & 15);
      const float bn = bias[n];
      #pragma unroll
      for (int j = 0; j < 4; j++) {
        const int m = m0 + wr*64 + mf*16 + (l >> 4)*4 + j;
        const float v = (acc[mf][nf][j] + bn) * scale;
        if (MODE == 0) {
          ((bf16*)outp)[(((size_t)(m >> 11) * NH + (n >> 6)) * SEQ + (m & (SEQ-1))) * HS + (n & 63)] = (bf16)v;
        } else if (MODE == 2) {
          ((bf16*)outp)[(((size_t)(m >> 11) * NH + (n >> 6)) * HS + (n & 63)) * SEQ + (m & (SEQ-1))] = (bf16)v;
        } else {
          ((float*)outp)[(size_t)m * HID + n] = v;
        }
      }
    }
  }
}

// ---------------- causal flash attention (tile-pipelined) ----------------
// Q,K: [B*NH][S][64] bf16 (Q pre-scaled by 0.125*log2e -> scores in base-2 domain).
// Vt: [B*NH][64][S] bf16. Out: [B*S][HID] bf16 merged heads.
// Block: 8 waves, two Q-tiles of 128 rows (paired p and 15-p).
// Pipeline: iter t computes QK^T(t+1) [MFMA] interleaved with softmax(t) [VALU] + PV(t).

__device__ __forceinline__ void qkt_tile(f32x4 (&out)[4], const bf16* ksb,
                                         const bf16x8 (&qf)[2], int k0, int q0,
                                         int w, int l) {
  #pragma unroll
  for (int nf = 0; nf < 4; nf++) out[nf] = f32x4{0.f, 0.f, 0.f, 0.f};
  #pragma unroll
  for (int ks = 0; ks < 2; ks++) {
    #pragma unroll
    for (int nf = 0; nf < 4; nf++) {
      const int kr = nf * 16 + (l & 15);
      const int cc = ks * 4 + (l >> 4);
      bf16x8 kf = *reinterpret_cast<const bf16x8*>(
          (const char*)ksb + kr * 128 + ((cc ^ (kr & 7)) * 16));
      out[nf] = mfma16(qf[ks], kf, out[nf]);
    }
  }
  if (k0 + 63 > q0 + 16 * w) {   // causal mask needed only near diagonal
    const int qg_ = q0 + 16 * w + 4 * (l >> 4);
    #pragma unroll
    for (int nf = 0; nf < 4; nf++) {
      const int kg_ = k0 + nf * 16 + (l & 15);
      #pragma unroll
      for (int j = 0; j < 4; j++)
        if (kg_ > qg_ + j) out[nf][j] = -1e30f;
    }
  }
}

__global__ __launch_bounds__(512) void k_attn(const bf16* __restrict__ Q,
                                              const bf16* __restrict__ K,
                                              const bf16* __restrict__ Vt,
                                              bf16* __restrict__ Aout) {
  const int bh = blockIdx.y;
  const int bx = blockIdx.x;
  const int tid = threadIdx.x, l = tid & 63, w = tid >> 6;

  __shared__ __align__(16) bf16 Qs[128*64];
  __shared__ __align__(16) bf16 Ks[2][64*64];
  __shared__ __align__(16) bf16 Vs[3][64*64];
  __shared__ __align__(16) bf16 Ps[128*64];

  const bf16* Qg = Q  + (size_t)bh * SEQ * HS;
  const bf16* Kg = K  + (size_t)bh * SEQ * HS;
  const bf16* Vg = Vt + (size_t)bh * HS * SEQ;   // [d][s]

  const int bb = bh >> 4, hh = bh & 15;
  const int sr  = tid >> 3;
  const int sc8 = tid & 7;
  const int swz = (sc8 ^ (sr & 7)) * 8;

  for (int pass = 0; pass < 2; ++pass) {
    const int p  = pass ? (15 - bx) : bx;
    const int q0 = p * 128;
    const int nt = 2 * p + 2;   // >= 2 always

    __syncthreads();   // close previous pass's LDS reads

    // stage Q + kv tile 0
    gl_lds16(Qg + (size_t)(q0 + sr)      * HS + swz, (char*)Qs        + w * 1024);
    gl_lds16(Qg + (size_t)(q0 + 64 + sr) * HS + swz, (char*)Qs + 8192 + w * 1024);
    gl_lds16(Kg + (size_t)sr * HS + swz,             (char*)Ks[0]     + w * 1024);
    gl_lds16(Vg + (size_t)sr * SEQ + swz,            (char*)Vs[0]     + w * 1024);
    __syncthreads();   // vmcnt drained: Q + kv0 ready

    // issue kv tile 1 early (published at iter-0 barrier)
    gl_lds16(Kg + (size_t)(64 + sr) * HS + swz, (char*)Ks[1] + w * 1024);
    gl_lds16(Vg + (size_t)sr * SEQ + 64 + swz,  (char*)Vs[1] + w * 1024);

    // hoist Q fragments
    bf16x8 qf[2];
    {
      const int row = 16 * w + (l & 15);
      #pragma unroll
      for (int ks = 0; ks < 2; ks++) {
        const int cc = ks * 4 + (l >> 4);
        qf[ks] = *reinterpret_cast<const bf16x8*>(
            (const char*)Qs + row * 128 + ((cc ^ (row & 7)) * 16));
      }
    }

    float m_r[4], l_r[4];
    f32x4 o[4] = {};
    #pragma unroll
    for (int j = 0; j < 4; j++) { m_r[j] = -1e30f; l_r[j] = 0.f; }

    // S for tile 0 (tile 0 is never fully masked for any wave)
    f32x4 scv[4];
    qkt_tile(scv, (const bf16*)Ks[0], qf, 0, q0, w, l);

    int vcur = 0, vpre = 2;   // t%3 and (t+2)%3
    for (int kt = 0; kt < nt; ++kt) {
      __syncthreads();  // publish kv(t+1); all reads of bufs being re-staged are closed

      // prefetch kv(t+2)
      if (kt + 2 < nt) {
        const int k2 = (kt + 2) * 64;
        gl_lds16(Kg + (size_t)(k2 + sr) * HS + swz, (char*)Ks[kt & 1] + w * 1024);
        gl_lds16(Vg + (size_t)sr * SEQ + k2 + swz,  (char*)Vs[vpre]   + w * 1024);
      }

      // QK^T for tile t+1 (MFMA; independent of softmax below -> interleaves)
      f32x4 nsc[4] = {};
      const bool next_live = (kt + 1 < nt) && (64 * (kt + 1) <= q0 + 16 * w + 15);
      if (next_live)
        qkt_tile(nsc, (const bf16*)Ks[(kt + 1) & 1], qf, 64 * (kt + 1), q0, w, l);

      // softmax + PV for tile t (base-2 domain)
      if (64 * kt <= q0 + 16 * w + 15) {
        float rmax[4];
        #pragma unroll
        for (int j = 0; j < 4; j++)
          rmax[j] = fmaxf(fmaxf(scv[0][j], scv[1][j]), fmaxf(scv[2][j], scv[3][j]));
        #pragma unroll
        for (int off = 1; off < 16; off <<= 1)
          #pragma unroll
          for (int j = 0; j < 4; j++)
            rmax[j] = fmaxf(rmax[j], __shfl_xor(rmax[j], off));

        // defer-max: only rescale when a row's max grew past threshold
        bool need = false;
        #pragma unroll
        for (int j = 0; j < 4; j++) need = need || (rmax[j] > m_r[j] + 8.0f);
        if (__any(need)) {
          float alpha[4];
          #pragma unroll
          for (int j = 0; j < 4; j++) {
            const float mn = fmaxf(m_r[j], rmax[j]);
            alpha[j] = __builtin_amdgcn_exp2f(m_r[j] - mn);
            m_r[j] = mn;
            l_r[j] *= alpha[j];
          }
          #pragma unroll
          for (int df = 0; df < 4; df++)
            #pragma unroll
            for (int j = 0; j < 4; j++)
              o[df][j] *= alpha[j];
        }

        float rsum[4] = {0.f, 0.f, 0.f, 0.f};
        #pragma unroll
        for (int nf = 0; nf < 4; nf++)
          #pragma unroll
          for (int j = 0; j < 4; j++) {
            const float pp = __builtin_amdgcn_exp2f(scv[nf][j] - m_r[j]);
            scv[nf][j] = pp;
            rsum[j] += pp;
          }
        #pragma unroll
        for (int off = 1; off < 16; off <<= 1)
          #pragma unroll
          for (int j = 0; j < 4; j++)
            rsum[j] += __shfl_xor(rsum[j], off);
        #pragma unroll
        for (int j = 0; j < 4; j++)
          l_r[j] += rsum[j];

        // P -> LDS (wave-private rows)
        #pragma unroll
        for (int nf = 0; nf < 4; nf++)
          #pragma unroll
          for (int j = 0; j < 4; j++) {
            const int row = 16 * w + 4 * (l >> 4) + j;
            const int cbyte = (nf * 16 + (l & 15)) * 2;
            *((bf16*)((char*)Ps + row * 128 + (cbyte ^ ((row & 7) << 4)))) = (bf16)scv[nf][j];
          }

        // O += P V
        #pragma unroll
        for (int ks = 0; ks < 2; ks++) {
          const int prow = 16 * w + (l & 15);
          bf16x8 pf = *reinterpret_cast<const bf16x8*>(
              (const char*)Ps + prow * 128 + (((ks * 4 + (l >> 4)) * 16) ^ ((prow & 7) << 4)));
          #pragma unroll
          for (int df = 0; df < 4; df++) {
            const int vr = df * 16 + (l & 15);
            const int cc = ks * 4 + (l >> 4);
            bf16x8 vf = *reinterpret_cast<const bf16x8*>(
                (const char*)Vs[vcur] + vr * 128 + ((cc ^ (vr & 7)) * 16));
            o[df] = mfma16(pf, vf, o[df]);
          }
        }
      }

      // shift pipeline
      #pragma unroll
      for (int nf = 0; nf < 4; nf++) scv[nf] = nsc[nf];
      vcur = (vcur == 2) ? 0 : vcur + 1;
      vpre = (vpre == 2) ? 0 : vpre + 1;
    }

    // epilogue: normalize, write merged-head bf16
    #pragma unroll
    for (int j = 0; j < 4; j++) {
      const float inv = 1.0f / l_r[j];
      const int q = q0 + 16 * w + 4 * (l >> 4) + j;
      #pragma unroll
      for (int df = 0; df < 4; df++) {
        const int dcol = df * 16 + (l & 15);
        Aout[(size_t)(bb * SEQ + q) * HID + hh * HS + dcol] = (bf16)(o[df][j] * inv);
      }
    }
  }
}

// ---------------- launch ----------------
extern "C" void kernel_launch(void* const* d_in, const int* in_sizes, int n_in,
                              void* d_out, int out_size, void* d_ws, size_t ws_size,
                              hipStream_t stream) {
  const float* x  = (const float*)d_in[0];
  const float* Wq = (const float*)d_in[1];
  const float* bq = (const float*)d_in[2];
  const float* Wk = (const float*)d_in[3];
  const float* bk = (const float*)d_in[4];
  const float* Wv = (const float*)d_in[5];
  const float* bv = (const float*)d_in[6];
  const float* Wo = (const float*)d_in[7];
  const float* bo = (const float*)d_in[8];

  char* ws = (char*)d_ws;
  const size_t MB = 1024 * 1024;
  bf16* xb  = (bf16*)(ws);             // 16MB; reused as attn-out
  bf16* wqb = (bf16*)(ws + 16*MB);
  bf16* wkb = (bf16*)(ws + 18*MB);
  bf16* wvb = (bf16*)(ws + 20*MB);
  bf16* wob = (bf16*)(ws + 22*MB);
  bf16* Qb  = (bf16*)(ws + 24*MB);     // [b][h][s][d]
  bf16* Kb  = (bf16*)(ws + 40*MB);     // [b][h][s][d]
  bf16* Vb  = (bf16*)(ws + 56*MB);     // [b][h][d][s]
  bf16* Ab  = xb;

  k_cvt<<<MR*HID/4/256, 256, 0, stream>>>(x, xb, MR*HID/4);
  k_cvt4<<<dim3(HID*KD/4/256, 4), 256, 0, stream>>>(Wq, Wk, Wv, Wo, wqb, wkb, wvb, wob, HID*KD/4);

  dim3 gg(MR/128, HID/128);
  // Q scaled by 0.125 * log2(e): softmax runs in base-2 domain
  k_gemm<0><<<gg, 256, 0, stream>>>(xb, wqb, bq, Qb, 0.18033688f);
  k_gemm<0><<<gg, 256, 0, stream>>>(xb, wkb, bk, Kb, 1.0f);
  k_gemm<2><<<gg, 256, 0, stream>>>(xb, wvb, bv, Vb, 1.0f);

  k_attn<<<dim3(8, BB*NH), 512, 0, stream>>>(Qb, Kb, Vb, Ab);

  k_gemm<1><<<gg, 256, 0, stream>>>(Ab, wob, bo, d_out, 1.0f);
}

// Round 4
// 220.587 us; speedup vs baseline: 1.1769x; 1.1769x over previous
//
#include <hip/hip_runtime.h>

#define NH 16
#define HS 64
#define HID 1024
#define SEQ 2048
#define BB 4
#define MR (BB*SEQ)   // 8192 rows
#define KD 1024
#define QSCALE 0.18033688f   // 0.125 * log2(e): softmax in base-2 domain

typedef __bf16 bf16;
typedef __attribute__((ext_vector_type(8))) __bf16 bf16x8;
typedef __attribute__((ext_vector_type(4))) __bf16 bf16x4;
typedef __attribute__((ext_vector_type(4))) float f32x4;
typedef __attribute__((ext_vector_type(4))) float f4;

typedef __attribute__((address_space(3))) unsigned int as3u;
typedef __attribute__((address_space(1))) unsigned int as1u;

__device__ __forceinline__ void gl_lds16(const void* g, void* l) {
  __builtin_amdgcn_global_load_lds((const as1u*)g, (as3u*)l, 16, 0, 0);
}

__device__ __forceinline__ f32x4 mfma16(bf16x8 a, bf16x8 b, f32x4 c) {
  return __builtin_amdgcn_mfma_f32_16x16x32_bf16(a, b, c, 0, 0, 0);
}

// ---------------- fp32 -> bf16 conversion ----------------
__global__ __launch_bounds__(256) void k_cvt(const float* __restrict__ in,
                                             bf16* __restrict__ out, int n4) {
  int i = blockIdx.x * 256 + threadIdx.x;
  if (i >= n4) return;
  f4 v = reinterpret_cast<const f4*>(in)[i];
  bf16x4 h;
  h[0] = (bf16)v[0]; h[1] = (bf16)v[1]; h[2] = (bf16)v[2]; h[3] = (bf16)v[3];
  reinterpret_cast<bf16x4*>(out)[i] = h;
}

__global__ __launch_bounds__(256) void k_cvt4(const float* __restrict__ w0, const float* __restrict__ w1,
                                              const float* __restrict__ w2, const float* __restrict__ w3,
                                              bf16* __restrict__ o0, bf16* __restrict__ o1,
                                              bf16* __restrict__ o2, bf16* __restrict__ o3, int n4) {
  int i = blockIdx.x * 256 + threadIdx.x;
  if (i >= n4) return;
  const float* in = (blockIdx.y == 0) ? w0 : (blockIdx.y == 1) ? w1 : (blockIdx.y == 2) ? w2 : w3;
  bf16* out = (blockIdx.y == 0) ? o0 : (blockIdx.y == 1) ? o1 : (blockIdx.y == 2) ? o2 : o3;
  f4 v = reinterpret_cast<const f4*>(in)[i];
  bf16x4 h;
  h[0] = (bf16)v[0]; h[1] = (bf16)v[1]; h[2] = (bf16)v[2]; h[3] = (bf16)v[3];
  reinterpret_cast<bf16x4*>(out)[i] = h;
}

// ---------------- fused QKV GEMM ----------------
// blockIdx.y: 0..7 -> Q (head-split, *QSCALE), 8..15 -> K (head-split), 16..23 -> V (transposed)
__global__ __launch_bounds__(256) void k_gemm_qkv(const bf16* __restrict__ A,
                                                  const bf16* __restrict__ wq, const bf16* __restrict__ wk,
                                                  const bf16* __restrict__ wv,
                                                  const float* __restrict__ bq, const float* __restrict__ bk,
                                                  const float* __restrict__ bv,
                                                  bf16* __restrict__ Qo, bf16* __restrict__ Ko,
                                                  bf16* __restrict__ Vo) {
  __shared__ __align__(16) bf16 As[128*32];
  __shared__ __align__(16) bf16 Bs[128*32];
  const int tid = threadIdx.x;
  const int l = tid & 63, w = tid >> 6;
  const int which = blockIdx.y >> 3;
  const int m0 = blockIdx.x * 128, n0 = (blockIdx.y & 7) * 128;
  const int wr = w >> 1, wc = w & 1;

  const bf16* Bw = (which == 0) ? wq : (which == 1) ? wk : wv;
  const float* bias = (which == 0) ? bq : (which == 1) ? bk : bv;

  f32x4 acc[4][4] = {};

  const int srow = 32*w + (l >> 2);
  const int scol = (l & 3) * 8;
  const bf16* Asrc = A  + (size_t)(m0 + srow) * KD + scol;
  const bf16* Bsrc = Bw + (size_t)(n0 + srow) * KD + scol;
  char* AsBase = (char*)As + (size_t)(w*2) * 1024;
  char* BsBase = (char*)Bs + (size_t)(w*2) * 1024;

  for (int kt = 0; kt < KD; kt += 32) {
    gl_lds16(Asrc + kt,                 AsBase);
    gl_lds16(Asrc + kt + (size_t)16*KD, AsBase + 1024);
    gl_lds16(Bsrc + kt,                 BsBase);
    gl_lds16(Bsrc + kt + (size_t)16*KD, BsBase + 1024);
    __syncthreads();

    bf16x8 af[4], bv_[4];
    const int koff = (l >> 4) * 8;
    #pragma unroll
    for (int mf = 0; mf < 4; mf++)
      af[mf] = *reinterpret_cast<const bf16x8*>(&As[(wr*64 + mf*16 + (l & 15))*32 + koff]);
    #pragma unroll
    for (int nf = 0; nf < 4; nf++)
      bv_[nf] = *reinterpret_cast<const bf16x8*>(&Bs[(wc*64 + nf*16 + (l & 15))*32 + koff]);
    #pragma unroll
    for (int mf = 0; mf < 4; mf++)
      #pragma unroll
      for (int nf = 0; nf < 4; nf++)
        acc[mf][nf] = mfma16(af[mf], bv_[nf], acc[mf][nf]);
    __syncthreads();
  }

  const float scale = (which == 0) ? QSCALE : 1.0f;
  #pragma unroll
  for (int mf = 0; mf < 4; mf++) {
    #pragma unroll
    for (int nf = 0; nf < 4; nf++) {
      const int n = n0 + wc*64 + nf*16 + (l & 15);
      const float bn = bias[n];
      #pragma unroll
      for (int j = 0; j < 4; j++) {
        const int m = m0 + wr*64 + mf*16 + (l >> 4)*4 + j;
        const float v = (acc[mf][nf][j] + bn) * scale;
        if (which == 2) {
          Vo[(((size_t)(m >> 11) * NH + (n >> 6)) * HS + (n & 63)) * SEQ + (m & (SEQ-1))] = (bf16)v;
        } else {
          bf16* dst = (which == 0) ? Qo : Ko;
          dst[(((size_t)(m >> 11) * NH + (n >> 6)) * SEQ + (m & (SEQ-1))) * HS + (n & 63)] = (bf16)v;
        }
      }
    }
  }
}

// ---------------- output-projection GEMM (f32 out) ----------------
__global__ __launch_bounds__(256) void k_gemm_o(const bf16* __restrict__ A,
                                                const bf16* __restrict__ Bw,
                                                const float* __restrict__ bias,
                                                float* __restrict__ outp) {
  __shared__ __align__(16) bf16 As[128*32];
  __shared__ __align__(16) bf16 Bs[128*32];
  const int tid = threadIdx.x;
  const int l = tid & 63, w = tid >> 6;
  const int m0 = blockIdx.x * 128, n0 = blockIdx.y * 128;
  const int wr = w >> 1, wc = w & 1;

  f32x4 acc[4][4] = {};

  const int srow = 32*w + (l >> 2);
  const int scol = (l & 3) * 8;
  const bf16* Asrc = A  + (size_t)(m0 + srow) * KD + scol;
  const bf16* Bsrc = Bw + (size_t)(n0 + srow) * KD + scol;
  char* AsBase = (char*)As + (size_t)(w*2) * 1024;
  char* BsBase = (char*)Bs + (size_t)(w*2) * 1024;

  for (int kt = 0; kt < KD; kt += 32) {
    gl_lds16(Asrc + kt,                 AsBase);
    gl_lds16(Asrc + kt + (size_t)16*KD, AsBase + 1024);
    gl_lds16(Bsrc + kt,                 BsBase);
    gl_lds16(Bsrc + kt + (size_t)16*KD, BsBase + 1024);
    __syncthreads();

    bf16x8 af[4], bv_[4];
    const int koff = (l >> 4) * 8;
    #pragma unroll
    for (int mf = 0; mf < 4; mf++)
      af[mf] = *reinterpret_cast<const bf16x8*>(&As[(wr*64 + mf*16 + (l & 15))*32 + koff]);
    #pragma unroll
    for (int nf = 0; nf < 4; nf++)
      bv_[nf] = *reinterpret_cast<const bf16x8*>(&Bs[(wc*64 + nf*16 + (l & 15))*32 + koff]);
    #pragma unroll
    for (int mf = 0; mf < 4; mf++)
      #pragma unroll
      for (int nf = 0; nf < 4; nf++)
        acc[mf][nf] = mfma16(af[mf], bv_[nf], acc[mf][nf]);
    __syncthreads();
  }

  #pragma unroll
  for (int mf = 0; mf < 4; mf++) {
    #pragma unroll
    for (int nf = 0; nf < 4; nf++) {
      const int n = n0 + wc*64 + nf*16 + (l & 15);
      const float bn = bias[n];
      #pragma unroll
      for (int j = 0; j < 4; j++) {
        const int m = m0 + wr*64 + mf*16 + (l >> 4)*4 + j;
        outp[(size_t)m * HID + n] = acc[mf][nf][j] + bn;
      }
    }
  }
}

// ---------------- causal flash attention (R2 structure, 48KB LDS) ----------------
// Q,K: [B*NH][S][64] bf16 (Q pre-scaled by QSCALE). Vt: [B*NH][64][S] bf16.
// Out: [B*S][HID] bf16. Block: 8 waves, two Q-tiles of 128 rows (paired p, 15-p).
__global__ __launch_bounds__(512) void k_attn(const bf16* __restrict__ Q,
                                              const bf16* __restrict__ K,
                                              const bf16* __restrict__ Vt,
                                              bf16* __restrict__ Aout) {
  const int bh = blockIdx.y;
  const int bx = blockIdx.x;
  const int tid = threadIdx.x, l = tid & 63, w = tid >> 6;

  __shared__ __align__(16) bf16 QPs[128*64];   // Q during hoist, then P
  __shared__ __align__(16) bf16 Ks[2][64*64];
  __shared__ __align__(16) bf16 Vs[2][64*64];

  const bf16* Qg = Q  + (size_t)bh * SEQ * HS;
  const bf16* Kg = K  + (size_t)bh * SEQ * HS;
  const bf16* Vg = Vt + (size_t)bh * HS * SEQ;   // [d][s]

  const int bb = bh >> 4, hh = bh & 15;
  const int sr  = tid >> 3;
  const int sc8 = tid & 7;
  const int swz = (sc8 ^ (sr & 7)) * 8;

  for (int pass = 0; pass < 2; ++pass) {
    const int p  = pass ? (15 - bx) : bx;
    const int q0 = p * 128;
    const int nt = 2 * p + 2;

    __syncthreads();   // close previous pass's LDS reads

    gl_lds16(Qg + (size_t)(q0 + sr)      * HS + swz, (char*)QPs        + w * 1024);
    gl_lds16(Qg + (size_t)(q0 + 64 + sr) * HS + swz, (char*)QPs + 8192 + w * 1024);
    gl_lds16(Kg + (size_t)sr * HS + swz,             (char*)Ks[0]      + w * 1024);
    gl_lds16(Vg + (size_t)sr * SEQ + swz,            (char*)Vs[0]      + w * 1024);
    __syncthreads();   // vmcnt drained: Q + kv0 ready

    // hoist Q fragments (wave w owns q rows 16w..16w+15)
    bf16x8 qf[2];
    {
      const int row = 16 * w + (l & 15);
      #pragma unroll
      for (int ks = 0; ks < 2; ks++) {
        const int cc = ks * 4 + (l >> 4);
        qf[ks] = *reinterpret_cast<const bf16x8*>(
            (const char*)QPs + row * 128 + ((cc ^ (row & 7)) * 16));
      }
    }

    float m_r[4], l_r[4];
    f32x4 o[4] = {};
    #pragma unroll
    for (int j = 0; j < 4; j++) { m_r[j] = -1e30f; l_r[j] = 0.f; }

    int cur = 0;
    for (int kt = 0; kt < nt; ++kt) {
      const int k0 = kt * 64;

      // prefetch next kv tile early (hides under this tile's compute)
      if (kt + 1 < nt) {
        const int k1 = k0 + 64;
        gl_lds16(Kg + (size_t)(k1 + sr) * HS + swz, (char*)Ks[cur ^ 1] + w * 1024);
        gl_lds16(Vg + (size_t)sr * SEQ + k1 + swz,  (char*)Vs[cur ^ 1] + w * 1024);
      }

      if (k0 <= q0 + 16 * w + 15) {   // wave-level tile skip
        // S = Q K^T
        f32x4 scv[4] = {};
        #pragma unroll
        for (int ks = 0; ks < 2; ks++) {
          #pragma unroll
          for (int nf = 0; nf < 4; nf++) {
            const int kr = nf * 16 + (l & 15);
            const int cc = ks * 4 + (l >> 4);
            bf16x8 kf = *reinterpret_cast<const bf16x8*>(
                (const char*)Ks[cur] + kr * 128 + ((cc ^ (kr & 7)) * 16));
            scv[nf] = mfma16(qf[ks], kf, scv[nf]);
          }
        }

        // causal mask near diagonal
        if (k0 + 63 > q0 + 16 * w) {
          const int qg_ = q0 + 16 * w + 4 * (l >> 4);
          #pragma unroll
          for (int nf = 0; nf < 4; nf++) {
            const int kg_ = k0 + nf * 16 + (l & 15);
            #pragma unroll
            for (int j = 0; j < 4; j++)
              if (kg_ > qg_ + j) scv[nf][j] = -1e30f;
          }
        }

        // online softmax, base-2 domain
        float rmax[4];
        #pragma unroll
        for (int j = 0; j < 4; j++)
          rmax[j] = fmaxf(fmaxf(scv[0][j], scv[1][j]), fmaxf(scv[2][j], scv[3][j]));
        #pragma unroll
        for (int off = 1; off < 16; off <<= 1)
          #pragma unroll
          for (int j = 0; j < 4; j++)
            rmax[j] = fmaxf(rmax[j], __shfl_xor(rmax[j], off));

        // defer-max (T13): rescale only when max grew past threshold
        bool need = false;
        #pragma unroll
        for (int j = 0; j < 4; j++) need = need || (rmax[j] > m_r[j] + 8.0f);
        if (__any(need)) {
          #pragma unroll
          for (int j = 0; j < 4; j++) {
            const float mn = fmaxf(m_r[j], rmax[j]);
            const float alpha = __builtin_amdgcn_exp2f(m_r[j] - mn);
            m_r[j] = mn;
            l_r[j] *= alpha;
            #pragma unroll
            for (int df = 0; df < 4; df++)
              o[df][j] *= alpha;
          }
        }

        float rsum[4] = {0.f, 0.f, 0.f, 0.f};
        #pragma unroll
        for (int nf = 0; nf < 4; nf++)
          #pragma unroll
          for (int j = 0; j < 4; j++) {
            const float pp = __builtin_amdgcn_exp2f(scv[nf][j] - m_r[j]);
            scv[nf][j] = pp;
            rsum[j] += pp;
          }
        #pragma unroll
        for (int off = 1; off < 16; off <<= 1)
          #pragma unroll
          for (int j = 0; j < 4; j++)
            rsum[j] += __shfl_xor(rsum[j], off);
        #pragma unroll
        for (int j = 0; j < 4; j++)
          l_r[j] += rsum[j];

        // P -> LDS (wave-private rows; Q already consumed)
        #pragma unroll
        for (int nf = 0; nf < 4; nf++)
          #pragma unroll
          for (int j = 0; j < 4; j++) {
            const int row = 16 * w + 4 * (l >> 4) + j;
            const int cbyte = (nf * 16 + (l & 15)) * 2;
            *((bf16*)((char*)QPs + row * 128 + (cbyte ^ ((row & 7) << 4)))) = (bf16)scv[nf][j];
          }

        // O += P V
        #pragma unroll
        for (int ks = 0; ks < 2; ks++) {
          const int prow = 16 * w + (l & 15);
          bf16x8 pf = *reinterpret_cast<const bf16x8*>(
              (const char*)QPs + prow * 128 + (((ks * 4 + (l >> 4)) * 16) ^ ((prow & 7) << 4)));
          #pragma unroll
          for (int df = 0; df < 4; df++) {
            const int vr = df * 16 + (l & 15);
            const int cc = ks * 4 + (l >> 4);
            bf16x8 vf = *reinterpret_cast<const bf16x8*>(
                (const char*)Vs[cur] + vr * 128 + ((cc ^ (vr & 7)) * 16));
            o[df] = mfma16(pf, vf, o[df]);
          }
        }
      }

      __syncthreads();   // publish prefetched buffer; close reads of current
      cur ^= 1;
    }

    // epilogue: normalize, write merged-head bf16
    #pragma unroll
    for (int j = 0; j < 4; j++) {
      const float inv = 1.0f / l_r[j];
      const int q = q0 + 16 * w + 4 * (l >> 4) + j;
      #pragma unroll
      for (int df = 0; df < 4; df++) {
        const int dcol = df * 16 + (l & 15);
        Aout[(size_t)(bb * SEQ + q) * HID + hh * HS + dcol] = (bf16)(o[df][j] * inv);
      }
    }
  }
}

// ---------------- launch ----------------
extern "C" void kernel_launch(void* const* d_in, const int* in_sizes, int n_in,
                              void* d_out, int out_size, void* d_ws, size_t ws_size,
                              hipStream_t stream) {
  const float* x  = (const float*)d_in[0];
  const float* Wq = (const float*)d_in[1];
  const float* bq = (const float*)d_in[2];
  const float* Wk = (const float*)d_in[3];
  const float* bk = (const float*)d_in[4];
  const float* Wv = (const float*)d_in[5];
  const float* bv = (const float*)d_in[6];
  const float* Wo = (const float*)d_in[7];
  const float* bo = (const float*)d_in[8];

  char* ws = (char*)d_ws;
  const size_t MB = 1024 * 1024;
  bf16* xb  = (bf16*)(ws);             // 16MB; reused as attn-out
  bf16* wqb = (bf16*)(ws + 16*MB);
  bf16* wkb = (bf16*)(ws + 18*MB);
  bf16* wvb = (bf16*)(ws + 20*MB);
  bf16* wob = (bf16*)(ws + 22*MB);
  bf16* Qb  = (bf16*)(ws + 24*MB);     // [b][h][s][d]
  bf16* Kb  = (bf16*)(ws + 40*MB);     // [b][h][s][d]
  bf16* Vb  = (bf16*)(ws + 56*MB);     // [b][h][d][s]
  bf16* Ab  = xb;

  k_cvt<<<MR*HID/4/256, 256, 0, stream>>>(x, xb, MR*HID/4);
  k_cvt4<<<dim3(HID*KD/4/256, 4), 256, 0, stream>>>(Wq, Wk, Wv, Wo, wqb, wkb, wvb, wob, HID*KD/4);

  k_gemm_qkv<<<dim3(MR/128, 24), 256, 0, stream>>>(xb, wqb, wkb, wvb, bq, bk, bv, Qb, Kb, Vb);

  k_attn<<<dim3(8, BB*NH), 512, 0, stream>>>(Qb, Kb, Vb, Ab);

  k_gemm_o<<<dim3(MR/128, HID/128), 256, 0, stream>>>(Ab, wob, bo, (float*)d_out);
}

// Round 6
// 179.748 us; speedup vs baseline: 1.4443x; 1.2272x over previous
//
#include <hip/hip_runtime.h>

#define NH 16
#define HS 64
#define HID 1024
#define SEQ 2048
#define BB 4
#define MR (BB*SEQ)   // 8192 rows
#define KD 1024
#define QSCALE 0.18033688f   // 0.125 * log2(e): softmax in base-2 domain

typedef __bf16 bf16;
typedef __attribute__((ext_vector_type(8))) __bf16 bf16x8;
typedef __attribute__((ext_vector_type(4))) __bf16 bf16x4;
typedef __attribute__((ext_vector_type(4))) float f32x4;
typedef __attribute__((ext_vector_type(16))) float f32x16;
typedef __attribute__((ext_vector_type(4))) float f4;
typedef __attribute__((ext_vector_type(2))) unsigned uintx2;

typedef __attribute__((address_space(3))) unsigned int as3u;
typedef __attribute__((address_space(1))) unsigned int as1u;

__device__ __forceinline__ void gl_lds16(const void* g, void* l) {
  __builtin_amdgcn_global_load_lds((const as1u*)g, (as3u*)l, 16, 0, 0);
}

__device__ __forceinline__ f32x4 mfma16(bf16x8 a, bf16x8 b, f32x4 c) {
  return __builtin_amdgcn_mfma_f32_16x16x32_bf16(a, b, c, 0, 0, 0);
}

__device__ __forceinline__ f32x16 mfma32(bf16x8 a, bf16x8 b, f32x16 c) {
  return __builtin_amdgcn_mfma_f32_32x32x16_bf16(a, b, c, 0, 0, 0);
}

// v_permlane32_swap_b32: dst.hi(lanes 32-63) <-> src.lo(lanes 0-31).
// Returns {new_dst, new_src}. Builtin guarantees distinct register allocation.
__device__ __forceinline__ uintx2 plswap(unsigned a, unsigned b) {
#if __has_builtin(__builtin_amdgcn_permlane32_swap)
  return __builtin_amdgcn_permlane32_swap(a, b, false, false);
#else
  asm volatile("v_permlane32_swap_b32 %0, %1" : "+&v"(a), "+v"(b));
  uintx2 r; r[0] = a; r[1] = b; return r;
#endif
}

// combine with partner lane (l^32): after plswap(x,x), r[0]=x[lane&31], r[1]=x[32+(lane&31)]
__device__ __forceinline__ float xmax32(float x) {
  uintx2 r = plswap(__float_as_uint(x), __float_as_uint(x));
  return fmaxf(__uint_as_float(r[0]), __uint_as_float(r[1]));
}
__device__ __forceinline__ float xadd32(float x) {
  uintx2 r = plswap(__float_as_uint(x), __float_as_uint(x));
  return __uint_as_float(r[0]) + __uint_as_float(r[1]);
}

__device__ __forceinline__ unsigned cvtpk(float lo, float hi) {
  unsigned r;
  asm("v_cvt_pk_bf16_f32 %0, %1, %2" : "=v"(r) : "v"(lo), "v"(hi));
  return r;
}

// ---------------- fp32 -> bf16 conversion ----------------
__global__ __launch_bounds__(256) void k_cvt(const float* __restrict__ in,
                                             bf16* __restrict__ out, int n4) {
  int i = blockIdx.x * 256 + threadIdx.x;
  if (i >= n4) return;
  f4 v = reinterpret_cast<const f4*>(in)[i];
  bf16x4 h;
  h[0] = (bf16)v[0]; h[1] = (bf16)v[1]; h[2] = (bf16)v[2]; h[3] = (bf16)v[3];
  reinterpret_cast<bf16x4*>(out)[i] = h;
}

__global__ __launch_bounds__(256) void k_cvt4(const float* __restrict__ w0, const float* __restrict__ w1,
                                              const float* __restrict__ w2, const float* __restrict__ w3,
                                              bf16* __restrict__ o0, bf16* __restrict__ o1,
                                              bf16* __restrict__ o2, bf16* __restrict__ o3, int n4) {
  int i = blockIdx.x * 256 + threadIdx.x;
  if (i >= n4) return;
  const float* in = (blockIdx.y == 0) ? w0 : (blockIdx.y == 1) ? w1 : (blockIdx.y == 2) ? w2 : w3;
  bf16* out = (blockIdx.y == 0) ? o0 : (blockIdx.y == 1) ? o1 : (blockIdx.y == 2) ? o2 : o3;
  f4 v = reinterpret_cast<const f4*>(in)[i];
  bf16x4 h;
  h[0] = (bf16)v[0]; h[1] = (bf16)v[1]; h[2] = (bf16)v[2]; h[3] = (bf16)v[3];
  reinterpret_cast<bf16x4*>(out)[i] = h;
}

// ---------------- fused QKV GEMM ----------------
__global__ __launch_bounds__(256) void k_gemm_qkv(const bf16* __restrict__ A,
                                                  const bf16* __restrict__ wq, const bf16* __restrict__ wk,
                                                  const bf16* __restrict__ wv,
                                                  const float* __restrict__ bq, const float* __restrict__ bk,
                                                  const float* __restrict__ bv,
                                                  bf16* __restrict__ Qo, bf16* __restrict__ Ko,
                                                  bf16* __restrict__ Vo) {
  __shared__ __align__(16) bf16 As[128*32];
  __shared__ __align__(16) bf16 Bs[128*32];
  const int tid = threadIdx.x;
  const int l = tid & 63, w = tid >> 6;
  const int which = blockIdx.y >> 3;
  const int m0 = blockIdx.x * 128, n0 = (blockIdx.y & 7) * 128;
  const int wr = w >> 1, wc = w & 1;

  const bf16* Bw = (which == 0) ? wq : (which == 1) ? wk : wv;
  const float* bias = (which == 0) ? bq : (which == 1) ? bk : bv;

  f32x4 acc[4][4] = {};

  const int srow = 32*w + (l >> 2);
  const int scol = (l & 3) * 8;
  const bf16* Asrc = A  + (size_t)(m0 + srow) * KD + scol;
  const bf16* Bsrc = Bw + (size_t)(n0 + srow) * KD + scol;
  char* AsBase = (char*)As + (size_t)(w*2) * 1024;
  char* BsBase = (char*)Bs + (size_t)(w*2) * 1024;

  for (int kt = 0; kt < KD; kt += 32) {
    gl_lds16(Asrc + kt,                 AsBase);
    gl_lds16(Asrc + kt + (size_t)16*KD, AsBase + 1024);
    gl_lds16(Bsrc + kt,                 BsBase);
    gl_lds16(Bsrc + kt + (size_t)16*KD, BsBase + 1024);
    __syncthreads();

    bf16x8 af[4], bv_[4];
    const int koff = (l >> 4) * 8;
    #pragma unroll
    for (int mf = 0; mf < 4; mf++)
      af[mf] = *reinterpret_cast<const bf16x8*>(&As[(wr*64 + mf*16 + (l & 15))*32 + koff]);
    #pragma unroll
    for (int nf = 0; nf < 4; nf++)
      bv_[nf] = *reinterpret_cast<const bf16x8*>(&Bs[(wc*64 + nf*16 + (l & 15))*32 + koff]);
    #pragma unroll
    for (int mf = 0; mf < 4; mf++)
      #pragma unroll
      for (int nf = 0; nf < 4; nf++)
        acc[mf][nf] = mfma16(af[mf], bv_[nf], acc[mf][nf]);
    __syncthreads();
  }

  const float scale = (which == 0) ? QSCALE : 1.0f;
  #pragma unroll
  for (int mf = 0; mf < 4; mf++) {
    #pragma unroll
    for (int nf = 0; nf < 4; nf++) {
      const int n = n0 + wc*64 + nf*16 + (l & 15);
      const float bn = bias[n];
      #pragma unroll
      for (int j = 0; j < 4; j++) {
        const int m = m0 + wr*64 + mf*16 + (l >> 4)*4 + j;
        const float v = (acc[mf][nf][j] + bn) * scale;
        if (which == 2) {
          Vo[(((size_t)(m >> 11) * NH + (n >> 6)) * HS + (n & 63)) * SEQ + (m & (SEQ-1))] = (bf16)v;
        } else {
          bf16* dst = (which == 0) ? Qo : Ko;
          dst[(((size_t)(m >> 11) * NH + (n >> 6)) * SEQ + (m & (SEQ-1))) * HS + (n & 63)] = (bf16)v;
        }
      }
    }
  }
}

// ---------------- output-projection GEMM (f32 out) ----------------
__global__ __launch_bounds__(256) void k_gemm_o(const bf16* __restrict__ A,
                                                const bf16* __restrict__ Bw,
                                                const float* __restrict__ bias,
                                                float* __restrict__ outp) {
  __shared__ __align__(16) bf16 As[128*32];
  __shared__ __align__(16) bf16 Bs[128*32];
  const int tid = threadIdx.x;
  const int l = tid & 63, w = tid >> 6;
  const int m0 = blockIdx.x * 128, n0 = blockIdx.y * 128;
  const int wr = w >> 1, wc = w & 1;

  f32x4 acc[4][4] = {};

  const int srow = 32*w + (l >> 2);
  const int scol = (l & 3) * 8;
  const bf16* Asrc = A  + (size_t)(m0 + srow) * KD + scol;
  const bf16* Bsrc = Bw + (size_t)(n0 + srow) * KD + scol;
  char* AsBase = (char*)As + (size_t)(w*2) * 1024;
  char* BsBase = (char*)Bs + (size_t)(w*2) * 1024;

  for (int kt = 0; kt < KD; kt += 32) {
    gl_lds16(Asrc + kt,                 AsBase);
    gl_lds16(Asrc + kt + (size_t)16*KD, AsBase + 1024);
    gl_lds16(Bsrc + kt,                 BsBase);
    gl_lds16(Bsrc + kt + (size_t)16*KD, BsBase + 1024);
    __syncthreads();

    bf16x8 af[4], bv_[4];
    const int koff = (l >> 4) * 8;
    #pragma unroll
    for (int mf = 0; mf < 4; mf++)
      af[mf] = *reinterpret_cast<const bf16x8*>(&As[(wr*64 + mf*16 + (l & 15))*32 + koff]);
    #pragma unroll
    for (int nf = 0; nf < 4; nf++)
      bv_[nf] = *reinterpret_cast<const bf16x8*>(&Bs[(wc*64 + nf*16 + (l & 15))*32 + koff]);
    #pragma unroll
    for (int mf = 0; mf < 4; mf++)
      #pragma unroll
      for (int nf = 0; nf < 4; nf++)
        acc[mf][nf] = mfma16(af[mf], bv_[nf], acc[mf][nf]);
    __syncthreads();
  }

  #pragma unroll
  for (int mf = 0; mf < 4; mf++) {
    #pragma unroll
    for (int nf = 0; nf < 4; nf++) {
      const int n = n0 + wc*64 + nf*16 + (l & 15);
      const float bn = bias[n];
      #pragma unroll
      for (int j = 0; j < 4; j++) {
        const int m = m0 + wr*64 + mf*16 + (l >> 4)*4 + j;
        outp[(size_t)m * HID + n] = acc[mf][nf][j] + bn;
      }
    }
  }
}

// ---------------- causal flash attention: 32x32 MFMA, swapped QK^T, reg softmax ----------------
__global__ __launch_bounds__(256, 2) void k_attn(const bf16* __restrict__ Q,
                                                 const bf16* __restrict__ K,
                                                 const bf16* __restrict__ Vt,
                                                 bf16* __restrict__ Aout) {
  const int bh = blockIdx.y;
  const int bx = blockIdx.x;
  const int tid = threadIdx.x, l = tid & 63, w = tid >> 6;
  const int hi = l >> 5;

  __shared__ __align__(16) bf16 Qs[128*64];
  __shared__ __align__(16) bf16 Ks[2][64*64];
  __shared__ __align__(16) bf16 Vs[2][64*64];

  const bf16* Qg = Q  + (size_t)bh * SEQ * HS;
  const bf16* Kg = K  + (size_t)bh * SEQ * HS;
  const bf16* Vg = Vt + (size_t)bh * HS * SEQ;   // [d][s]

  const int bb = bh >> 4, hh = bh & 15;
  const int sr  = tid >> 3;                    // 0..31
  const int swz = ((tid & 7) ^ (sr & 7)) * 8;  // pre-swizzled source col (elements)

  for (int pass = 0; pass < 2; ++pass) {
    const int p_ = pass ? (15 - bx) : bx;
    const int q0 = p_ * 128;
    const int nt = 2 * p_ + 2;

    __syncthreads();   // close previous pass's LDS reads

    #pragma unroll
    for (int i = 0; i < 4; i++)   // Q: 128 rows
      gl_lds16(Qg + (size_t)(q0 + 32*i + sr) * HS + swz, (char*)Qs + i*4096 + w*1024);
    #pragma unroll
    for (int i = 0; i < 2; i++) { // K0, V0: 64 rows each
      gl_lds16(Kg + (size_t)(32*i + sr) * HS + swz,  (char*)Ks[0] + i*4096 + w*1024);
      gl_lds16(Vg + (size_t)(32*i + sr) * SEQ + swz, (char*)Vs[0] + i*4096 + w*1024);
    }
    __syncthreads();   // vmcnt drained

    // hoist Q B-frags: lane holds Q[q = w*32+(l&31)][d = 16m+8hi+0..7]
    bf16x8 qf[4];
    {
      const int qrow = w*32 + (l & 31);
      #pragma unroll
      for (int m = 0; m < 4; m++) {
        const int cc = 2*m + hi;
        qf[m] = *(const bf16x8*)((const char*)Qs + qrow*128 + ((cc ^ (qrow & 7))*16));
      }
    }

    float m_r = -1e30f, l_r = 0.f;
    f32x16 o[2] = {};
    const int qmax = q0 + w*32 + 31;
    const int qg   = q0 + w*32 + (l & 31);

    int cur = 0;
    for (int kt = 0; kt < nt; ++kt) {
      const int k0 = kt * 64;

      if (kt + 1 < nt) {   // prefetch next kv tile (hides under compute)
        const int k1 = k0 + 64;
        #pragma unroll
        for (int i = 0; i < 2; i++) {
          gl_lds16(Kg + (size_t)(k1 + 32*i + sr) * HS + swz,  (char*)Ks[cur^1] + i*4096 + w*1024);
          gl_lds16(Vg + (size_t)(32*i + sr) * SEQ + k1 + swz, (char*)Vs[cur^1] + i*4096 + w*1024);
        }
      }

      if (k0 <= qmax) {
        // S^T = K·Q : p[b] col q=l&31, row kv = 32b + (r&3)+8*(r>>2)+4*hi
        f32x16 p[2] = {};
        #pragma unroll
        for (int b = 0; b < 2; b++) {
          #pragma unroll
          for (int m = 0; m < 4; m++) {
            const int row = 32*b + (l & 31);
            const int cc = 2*m + hi;
            bf16x8 kf = *(const bf16x8*)((const char*)Ks[cur] + row*128 + ((cc ^ (row & 7))*16));
            p[b] = mfma32(kf, qf[m], p[b]);
          }
        }

        if (k0 + 63 > q0 + w*32) {   // causal mask (near-diagonal tiles only)
          #pragma unroll
          for (int b = 0; b < 2; b++)
            #pragma unroll
            for (int r = 0; r < 16; r++) {
              const int kg = k0 + 32*b + (r & 3) + 8*(r >> 2) + 4*hi;
              if (kg > qg) p[b][r] = -1e30f;
            }
        }

        // row max: 31 local fmax + 1 permlane swap
        float rloc = -1e30f;
        #pragma unroll
        for (int b = 0; b < 2; b++)
          #pragma unroll
          for (int r = 0; r < 16; r++) rloc = fmaxf(rloc, p[b][r]);
        const float rmax = xmax32(rloc);

        // defer-max (T13)
        if (__any(rmax > m_r + 8.0f)) {
          const float mn = fmaxf(m_r, rmax);
          const float alpha = __builtin_amdgcn_exp2f(m_r - mn);
          m_r = mn;
          l_r *= alpha;
          #pragma unroll
          for (int r = 0; r < 16; r++) {
            const float ar = __shfl(alpha, (r & 3) + 8*(r >> 2) + 4*hi);
            o[0][r] *= ar; o[1][r] *= ar;
          }
        }

        float sloc = 0.f;
        #pragma unroll
        for (int b = 0; b < 2; b++)
          #pragma unroll
          for (int r = 0; r < 16; r++) {
            const float e = __builtin_amdgcn_exp2f(p[b][r] - m_r);
            p[b][r] = e;
            sloc += e;
          }
        l_r += xadd32(sloc);

        // P -> PV A-frags in registers: 16 cvt_pk + 8 permlane32_swap
        bf16x8 pa[4];
        #pragma unroll
        for (int c = 0; c < 4; c++) {
          const int b = c >> 1, R = (c & 1) * 8;
          unsigned w01 = cvtpk(p[b][R+0], p[b][R+1]);
          unsigned w23 = cvtpk(p[b][R+2], p[b][R+3]);
          unsigned w89 = cvtpk(p[b][R+4], p[b][R+5]);
          unsigned wab = cvtpk(p[b][R+6], p[b][R+7]);
          uintx2 s1 = plswap(w01, w89);
          uintx2 s2 = plswap(w23, wab);
          union { unsigned u[4]; bf16x8 v; } uu;
          uu.u[0] = s1[0]; uu.u[1] = s2[0]; uu.u[2] = s1[1]; uu.u[3] = s2[1];
          pa[c] = uu.v;
        }

        // O += P·V  (A rows q=l&31 match pa; B from Vs[d][kv])
        #pragma unroll
        for (int d = 0; d < 2; d++) {
          #pragma unroll
          for (int c = 0; c < 4; c++) {
            const int row = 32*d + (l & 31);
            const int cc = 2*c + hi;
            bf16x8 vf = *(const bf16x8*)((const char*)Vs[cur] + row*128 + ((cc ^ (row & 7))*16));
            o[d] = mfma32(pa[c], vf, o[d]);
          }
        }
      }

      __syncthreads();   // publish prefetched buffer; close reads of current
      cur ^= 1;
    }

    // epilogue: O[q = crow(r,hi)][d = 32d+(l&31)], normalize via shfl'd 1/l_r
    const float inv = 1.0f / l_r;
    #pragma unroll
    for (int r = 0; r < 16; r++) {
      const int qr = (r & 3) + 8*(r >> 2) + 4*hi;
      const float ir = __shfl(inv, qr);
      const int q = q0 + w*32 + qr;
      #pragma unroll
      for (int d = 0; d < 2; d++)
        Aout[(size_t)(bb*SEQ + q)*HID + hh*HS + d*32 + (l & 31)] = (bf16)(o[d][r] * ir);
    }
  }
}

// ---------------- launch ----------------
extern "C" void kernel_launch(void* const* d_in, const int* in_sizes, int n_in,
                              void* d_out, int out_size, void* d_ws, size_t ws_size,
                              hipStream_t stream) {
  const float* x  = (const float*)d_in[0];
  const float* Wq = (const float*)d_in[1];
  const float* bq = (const float*)d_in[2];
  const float* Wk = (const float*)d_in[3];
  const float* bk = (const float*)d_in[4];
  const float* Wv = (const float*)d_in[5];
  const float* bv = (const float*)d_in[6];
  const float* Wo = (const float*)d_in[7];
  const float* bo = (const float*)d_in[8];

  char* ws = (char*)d_ws;
  const size_t MB = 1024 * 1024;
  bf16* xb  = (bf16*)(ws);             // 16MB; reused as attn-out
  bf16* wqb = (bf16*)(ws + 16*MB);
  bf16* wkb = (bf16*)(ws + 18*MB);
  bf16* wvb = (bf16*)(ws + 20*MB);
  bf16* wob = (bf16*)(ws + 22*MB);
  bf16* Qb  = (bf16*)(ws + 24*MB);     // [b][h][s][d]
  bf16* Kb  = (bf16*)(ws + 40*MB);     // [b][h][s][d]
  bf16* Vb  = (bf16*)(ws + 56*MB);     // [b][h][d][s]
  bf16* Ab  = xb;

  k_cvt<<<MR*HID/4/256, 256, 0, stream>>>(x, xb, MR*HID/4);
  k_cvt4<<<dim3(HID*KD/4/256, 4), 256, 0, stream>>>(Wq, Wk, Wv, Wo, wqb, wkb, wvb, wob, HID*KD/4);

  k_gemm_qkv<<<dim3(MR/128, 24), 256, 0, stream>>>(xb, wqb, wkb, wvb, bq, bk, bv, Qb, Kb, Vb);

  k_attn<<<dim3(8, BB*NH), 256, 0, stream>>>(Qb, Kb, Vb, Ab);

  k_gemm_o<<<dim3(MR/128, HID/128), 256, 0, stream>>>(Ab, wob, bo, (float*)d_out);
}

// Round 7
// 170.714 us; speedup vs baseline: 1.5207x; 1.0529x over previous
//
#include <hip/hip_runtime.h>

#define NH 16
#define HS 64
#define HID 1024
#define SEQ 2048
#define BB 4
#define MR (BB*SEQ)   // 8192 rows
#define KD 1024
#define NT 32         // K-tiles of 32
#define QSCALE 0.18033688f   // 0.125 * log2(e): softmax in base-2 domain

typedef __bf16 bf16;
typedef __attribute__((ext_vector_type(8))) __bf16 bf16x8;
typedef __attribute__((ext_vector_type(4))) __bf16 bf16x4;
typedef __attribute__((ext_vector_type(4))) float f32x4;
typedef __attribute__((ext_vector_type(16))) float f32x16;
typedef __attribute__((ext_vector_type(4))) float f4;
typedef __attribute__((ext_vector_type(2))) unsigned uintx2;

typedef __attribute__((address_space(3))) unsigned int as3u;
typedef __attribute__((address_space(1))) unsigned int as1u;

__device__ __forceinline__ void gl_lds16(const void* g, void* l) {
  __builtin_amdgcn_global_load_lds((const as1u*)g, (as3u*)l, 16, 0, 0);
}

__device__ __forceinline__ f32x4 mfma16(bf16x8 a, bf16x8 b, f32x4 c) {
  return __builtin_amdgcn_mfma_f32_16x16x32_bf16(a, b, c, 0, 0, 0);
}

__device__ __forceinline__ f32x16 mfma32(bf16x8 a, bf16x8 b, f32x16 c) {
  return __builtin_amdgcn_mfma_f32_32x32x16_bf16(a, b, c, 0, 0, 0);
}

__device__ __forceinline__ uintx2 plswap(unsigned a, unsigned b) {
#if __has_builtin(__builtin_amdgcn_permlane32_swap)
  return __builtin_amdgcn_permlane32_swap(a, b, false, false);
#else
  asm volatile("v_permlane32_swap_b32 %0, %1" : "+&v"(a), "+v"(b));
  uintx2 r; r[0] = a; r[1] = b; return r;
#endif
}

__device__ __forceinline__ float xmax32(float x) {
  uintx2 r = plswap(__float_as_uint(x), __float_as_uint(x));
  return fmaxf(__uint_as_float(r[0]), __uint_as_float(r[1]));
}
__device__ __forceinline__ float xadd32(float x) {
  uintx2 r = plswap(__float_as_uint(x), __float_as_uint(x));
  return __uint_as_float(r[0]) + __uint_as_float(r[1]);
}

__device__ __forceinline__ unsigned cvtpk(float lo, float hi) {
  unsigned r;
  asm("v_cvt_pk_bf16_f32 %0, %1, %2" : "=v"(r) : "v"(lo), "v"(hi));
  return r;
}

// ---------------- fp32 -> bf16 conversion ----------------
__global__ __launch_bounds__(256) void k_cvt(const float* __restrict__ in,
                                             bf16* __restrict__ out, int n4) {
  int i = blockIdx.x * 256 + threadIdx.x;
  if (i >= n4) return;
  f4 v = reinterpret_cast<const f4*>(in)[i];
  bf16x4 h;
  h[0] = (bf16)v[0]; h[1] = (bf16)v[1]; h[2] = (bf16)v[2]; h[3] = (bf16)v[3];
  reinterpret_cast<bf16x4*>(out)[i] = h;
}

__global__ __launch_bounds__(256) void k_cvt4(const float* __restrict__ w0, const float* __restrict__ w1,
                                              const float* __restrict__ w2, const float* __restrict__ w3,
                                              bf16* __restrict__ o0, bf16* __restrict__ o1,
                                              bf16* __restrict__ o2, bf16* __restrict__ o3, int n4) {
  int i = blockIdx.x * 256 + threadIdx.x;
  if (i >= n4) return;
  const float* in = (blockIdx.y == 0) ? w0 : (blockIdx.y == 1) ? w1 : (blockIdx.y == 2) ? w2 : w3;
  bf16* out = (blockIdx.y == 0) ? o0 : (blockIdx.y == 1) ? o1 : (blockIdx.y == 2) ? o2 : o3;
  f4 v = reinterpret_cast<const f4*>(in)[i];
  bf16x4 h;
  h[0] = (bf16)v[0]; h[1] = (bf16)v[1]; h[2] = (bf16)v[2]; h[3] = (bf16)v[3];
  reinterpret_cast<bf16x4*>(out)[i] = h;
}

// ---------------- pipelined NT GEMM: BM=128, BN=256, BK=32, 3-buffer, counted vmcnt ----------------
// MODE 0: QKV fused — blockIdx.y: y>>2 selects {Q,K,V}, (y&3)*256 = n0.
//         Q/K -> head-split bf16 [b][h][s][d] (Q scaled); V -> transposed [b][h][d][s].
// MODE 1: O-projection — f32 flat out, blockIdx.y*256 = n0.
template<int MODE>
__global__ __launch_bounds__(512, 4) void k_gemm_p(const bf16* __restrict__ A,
                                                   const bf16* __restrict__ w0, const bf16* __restrict__ w1,
                                                   const bf16* __restrict__ w2,
                                                   const float* __restrict__ b0, const float* __restrict__ b1,
                                                   const float* __restrict__ b2p,
                                                   void* __restrict__ o0, void* __restrict__ o1,
                                                   void* __restrict__ o2) {
  __shared__ __align__(16) bf16 As[3][128*32];
  __shared__ __align__(16) bf16 Bs[3][256*32];
  const int tid = threadIdx.x, l = tid & 63, w = tid >> 6;
  const int wr = w >> 2, wc = w & 3;
  const int m0 = blockIdx.x * 128;
  const int ny = blockIdx.y;
  const int which = (MODE == 0) ? (ny >> 2) : 0;
  const int n0 = (MODE == 0) ? (ny & 3) * 256 : ny * 256;
  const bf16* Bw = (MODE == 1) ? w0 : (which == 0 ? w0 : which == 1 ? w1 : w2);
  const float* bias = (MODE == 1) ? b0 : (which == 0 ? b0 : which == 1 ? b1 : b2p);

  // staging source (pre-swizzled column): LDS[r][c] = global[r][c ^ ((r>>1)&3)]
  const int sra = tid >> 2;                               // 0..127
  const int sca = (tid & 3) ^ ((sra >> 1) & 3);           // swizzled 16B-chunk
  const bf16* Ag = A  + (size_t)(m0 + sra) * KD + sca * 8;
  const bf16* Bg = Bw + (size_t)(n0 + sra) * KD + sca * 8;

  // prologue: stage tiles 0 and 1 (3 loads each; 6 outstanding)
  gl_lds16(Ag,                        (char*)As[0] + w * 1024);
  gl_lds16(Bg,                        (char*)Bs[0] + w * 1024);
  gl_lds16(Bg + (size_t)128 * KD,     (char*)Bs[0] + 8192 + w * 1024);
  gl_lds16(Ag + 32,                   (char*)As[1] + w * 1024);
  gl_lds16(Bg + 32,                   (char*)Bs[1] + w * 1024);
  gl_lds16(Bg + (size_t)128 * KD + 32, (char*)Bs[1] + 8192 + w * 1024);

  f32x4 acc[4][4] = {};

  // loop-invariant read addressing (per-lane swizzled)
  const int la = l & 15, lg = l >> 4;

  for (int t = 0; t < NT; ++t) {
    const int bq = t % 3;
    if (t < NT - 1) { asm volatile("s_waitcnt vmcnt(3)" ::: "memory"); }
    else            { asm volatile("s_waitcnt vmcnt(0)" ::: "memory"); }
    __builtin_amdgcn_sched_barrier(0);
    __builtin_amdgcn_s_barrier();
    __builtin_amdgcn_sched_barrier(0);

    // ---- phase 0: A frags (4) + B frags 0,1 ----
    bf16x8 af[4], bf_[2];
    #pragma unroll
    for (int mf = 0; mf < 4; mf++) {
      const int ra = wr * 64 + mf * 16 + la;
      const int ca = lg ^ ((ra >> 1) & 3);
      af[mf] = *(const bf16x8*)((const char*)As[bq] + ra * 64 + ca * 16);
    }
    #pragma unroll
    for (int nf = 0; nf < 2; nf++) {
      const int rb = wc * 64 + nf * 16 + la;
      const int cb = lg ^ ((rb >> 1) & 3);
      bf_[nf] = *(const bf16x8*)((const char*)Bs[bq] + rb * 64 + cb * 16);
    }
    const int t2 = t + 2;
    if (t2 < NT) {   // stage tile t+2 (its buffer was released at this tile's barrier)
      const int b2 = t2 % 3;
      gl_lds16(Ag + t2 * 32, (char*)As[b2] + w * 1024);
      gl_lds16(Bg + t2 * 32, (char*)Bs[b2] + w * 1024);
    }
    asm volatile("s_waitcnt lgkmcnt(0)" ::: "memory");
    __builtin_amdgcn_sched_barrier(0);
    __builtin_amdgcn_s_setprio(1);
    #pragma unroll
    for (int mf = 0; mf < 4; mf++) {
      acc[mf][0] = mfma16(af[mf], bf_[0], acc[mf][0]);
      acc[mf][1] = mfma16(af[mf], bf_[1], acc[mf][1]);
    }
    __builtin_amdgcn_s_setprio(0);

    // ---- phase 1: B frags 2,3 ----
    #pragma unroll
    for (int nf = 0; nf < 2; nf++) {
      const int rb = wc * 64 + (nf + 2) * 16 + la;
      const int cb = lg ^ ((rb >> 1) & 3);
      bf_[nf] = *(const bf16x8*)((const char*)Bs[bq] + rb * 64 + cb * 16);
    }
    if (t2 < NT) {
      const int b2 = t2 % 3;
      gl_lds16(Bg + (size_t)128 * KD + t2 * 32, (char*)Bs[b2] + 8192 + w * 1024);
    }
    asm volatile("s_waitcnt lgkmcnt(0)" ::: "memory");
    __builtin_amdgcn_sched_barrier(0);
    __builtin_amdgcn_s_setprio(1);
    #pragma unroll
    for (int mf = 0; mf < 4; mf++) {
      acc[mf][2] = mfma16(af[mf], bf_[0], acc[mf][2]);
      acc[mf][3] = mfma16(af[mf], bf_[1], acc[mf][3]);
    }
    __builtin_amdgcn_s_setprio(0);
  }

  // ---- epilogue ----
  const float scale = (MODE == 0 && which == 0) ? QSCALE : 1.0f;
  #pragma unroll
  for (int mf = 0; mf < 4; mf++) {
    #pragma unroll
    for (int nf = 0; nf < 4; nf++) {
      const int n = n0 + wc * 64 + nf * 16 + la;
      const float bn = bias[n];
      #pragma unroll
      for (int j = 0; j < 4; j++) {
        const int m = m0 + wr * 64 + mf * 16 + lg * 4 + j;
        const float v = (acc[mf][nf][j] + bn) * scale;
        if (MODE == 0) {
          if (which == 2) {
            ((bf16*)o2)[(((size_t)(m >> 11) * NH + (n >> 6)) * HS + (n & 63)) * SEQ + (m & (SEQ - 1))] = (bf16)v;
          } else {
            bf16* dst = (which == 0) ? (bf16*)o0 : (bf16*)o1;
            dst[(((size_t)(m >> 11) * NH + (n >> 6)) * SEQ + (m & (SEQ - 1))) * HS + (n & 63)] = (bf16)v;
          }
        } else {
          ((float*)o0)[(size_t)m * HID + n] = v;
        }
      }
    }
  }
}

// ---------------- causal flash attention: 32x32 MFMA, swapped QK^T, reg softmax ----------------
__global__ __launch_bounds__(256, 2) void k_attn(const bf16* __restrict__ Q,
                                                 const bf16* __restrict__ K,
                                                 const bf16* __restrict__ Vt,
                                                 bf16* __restrict__ Aout) {
  const int bh = blockIdx.y;
  const int bx = blockIdx.x;
  const int tid = threadIdx.x, l = tid & 63, w = tid >> 6;
  const int hi = l >> 5;

  __shared__ __align__(16) bf16 Qs[128*64];
  __shared__ __align__(16) bf16 Ks[2][64*64];
  __shared__ __align__(16) bf16 Vs[2][64*64];

  const bf16* Qg = Q  + (size_t)bh * SEQ * HS;
  const bf16* Kg = K  + (size_t)bh * SEQ * HS;
  const bf16* Vg = Vt + (size_t)bh * HS * SEQ;   // [d][s]

  const int bb = bh >> 4, hh = bh & 15;
  const int sr  = tid >> 3;                    // 0..31
  const int swz = ((tid & 7) ^ (sr & 7)) * 8;  // pre-swizzled source col (elements)

  for (int pass = 0; pass < 2; ++pass) {
    const int p_ = pass ? (15 - bx) : bx;
    const int q0 = p_ * 128;
    const int nt = 2 * p_ + 2;

    __syncthreads();   // close previous pass's LDS reads

    #pragma unroll
    for (int i = 0; i < 4; i++)   // Q: 128 rows
      gl_lds16(Qg + (size_t)(q0 + 32*i + sr) * HS + swz, (char*)Qs + i*4096 + w*1024);
    #pragma unroll
    for (int i = 0; i < 2; i++) { // K0, V0: 64 rows each
      gl_lds16(Kg + (size_t)(32*i + sr) * HS + swz,  (char*)Ks[0] + i*4096 + w*1024);
      gl_lds16(Vg + (size_t)(32*i + sr) * SEQ + swz, (char*)Vs[0] + i*4096 + w*1024);
    }
    __syncthreads();   // vmcnt drained

    // hoist Q B-frags: lane holds Q[q = w*32+(l&31)][d = 16m+8hi+0..7]
    bf16x8 qf[4];
    {
      const int qrow = w*32 + (l & 31);
      #pragma unroll
      for (int m = 0; m < 4; m++) {
        const int cc = 2*m + hi;
        qf[m] = *(const bf16x8*)((const char*)Qs + qrow*128 + ((cc ^ (qrow & 7))*16));
      }
    }

    float m_r = -1e30f, l_r = 0.f;
    f32x16 o[2] = {};
    const int qmax = q0 + w*32 + 31;
    const int qg   = q0 + w*32 + (l & 31);

    int cur = 0;
    for (int kt = 0; kt < nt; ++kt) {
      const int k0 = kt * 64;

      if (kt + 1 < nt) {   // prefetch next kv tile (hides under compute)
        const int k1 = k0 + 64;
        #pragma unroll
        for (int i = 0; i < 2; i++) {
          gl_lds16(Kg + (size_t)(k1 + 32*i + sr) * HS + swz,  (char*)Ks[cur^1] + i*4096 + w*1024);
          gl_lds16(Vg + (size_t)(32*i + sr) * SEQ + k1 + swz, (char*)Vs[cur^1] + i*4096 + w*1024);
        }
      }

      if (k0 <= qmax) {
        // S^T = K·Q : p[b] col q=l&31, row kv = 32b + (r&3)+8*(r>>2)+4*hi
        f32x16 p[2] = {};
        #pragma unroll
        for (int b = 0; b < 2; b++) {
          #pragma unroll
          for (int m = 0; m < 4; m++) {
            const int row = 32*b + (l & 31);
            const int cc = 2*m + hi;
            bf16x8 kf = *(const bf16x8*)((const char*)Ks[cur] + row*128 + ((cc ^ (row & 7))*16));
            p[b] = mfma32(kf, qf[m], p[b]);
          }
        }

        if (k0 + 63 > q0 + w*32) {   // causal mask (near-diagonal tiles only)
          #pragma unroll
          for (int b = 0; b < 2; b++)
            #pragma unroll
            for (int r = 0; r < 16; r++) {
              const int kg = k0 + 32*b + (r & 3) + 8*(r >> 2) + 4*hi;
              if (kg > qg) p[b][r] = -1e30f;
            }
        }

        // row max: 31 local fmax + 1 permlane swap
        float rloc = -1e30f;
        #pragma unroll
        for (int b = 0; b < 2; b++)
          #pragma unroll
          for (int r = 0; r < 16; r++) rloc = fmaxf(rloc, p[b][r]);
        const float rmax = xmax32(rloc);

        // defer-max (T13)
        if (__any(rmax > m_r + 8.0f)) {
          const float mn = fmaxf(m_r, rmax);
          const float alpha = __builtin_amdgcn_exp2f(m_r - mn);
          m_r = mn;
          l_r *= alpha;
          #pragma unroll
          for (int r = 0; r < 16; r++) {
            const float ar = __shfl(alpha, (r & 3) + 8*(r >> 2) + 4*hi);
            o[0][r] *= ar; o[1][r] *= ar;
          }
        }

        float sloc = 0.f;
        #pragma unroll
        for (int b = 0; b < 2; b++)
          #pragma unroll
          for (int r = 0; r < 16; r++) {
            const float e = __builtin_amdgcn_exp2f(p[b][r] - m_r);
            p[b][r] = e;
            sloc += e;
          }
        l_r += xadd32(sloc);

        // P -> PV A-frags in registers: 16 cvt_pk + 8 permlane32_swap
        bf16x8 pa[4];
        #pragma unroll
        for (int c = 0; c < 4; c++) {
          const int b = c >> 1, R = (c & 1) * 8;
          unsigned w01 = cvtpk(p[b][R+0], p[b][R+1]);
          unsigned w23 = cvtpk(p[b][R+2], p[b][R+3]);
          unsigned w89 = cvtpk(p[b][R+4], p[b][R+5]);
          unsigned wab = cvtpk(p[b][R+6], p[b][R+7]);
          uintx2 s1 = plswap(w01, w89);
          uintx2 s2 = plswap(w23, wab);
          union { unsigned u[4]; bf16x8 v; } uu;
          uu.u[0] = s1[0]; uu.u[1] = s2[0]; uu.u[2] = s1[1]; uu.u[3] = s2[1];
          pa[c] = uu.v;
        }

        // O += P·V  (A rows q=l&31 match pa; B from Vs[d][kv])
        #pragma unroll
        for (int d = 0; d < 2; d++) {
          #pragma unroll
          for (int c = 0; c < 4; c++) {
            const int row = 32*d + (l & 31);
            const int cc = 2*c + hi;
            bf16x8 vf = *(const bf16x8*)((const char*)Vs[cur] + row*128 + ((cc ^ (row & 7))*16));
            o[d] = mfma32(pa[c], vf, o[d]);
          }
        }
      }

      __syncthreads();   // publish prefetched buffer; close reads of current
      cur ^= 1;
    }

    // epilogue: O[q = crow(r,hi)][d = 32d+(l&31)], normalize via shfl'd 1/l_r
    const float inv = 1.0f / l_r;
    #pragma unroll
    for (int r = 0; r < 16; r++) {
      const int qr = (r & 3) + 8*(r >> 2) + 4*hi;
      const float ir = __shfl(inv, qr);
      const int q = q0 + w*32 + qr;
      #pragma unroll
      for (int d = 0; d < 2; d++)
        Aout[(size_t)(bb*SEQ + q)*HID + hh*HS + d*32 + (l & 31)] = (bf16)(o[d][r] * ir);
    }
  }
}

// ---------------- launch ----------------
extern "C" void kernel_launch(void* const* d_in, const int* in_sizes, int n_in,
                              void* d_out, int out_size, void* d_ws, size_t ws_size,
                              hipStream_t stream) {
  const float* x  = (const float*)d_in[0];
  const float* Wq = (const float*)d_in[1];
  const float* bq = (const float*)d_in[2];
  const float* Wk = (const float*)d_in[3];
  const float* bk = (const float*)d_in[4];
  const float* Wv = (const float*)d_in[5];
  const float* bv = (const float*)d_in[6];
  const float* Wo = (const float*)d_in[7];
  const float* bo = (const float*)d_in[8];

  char* ws = (char*)d_ws;
  const size_t MB = 1024 * 1024;
  bf16* xb  = (bf16*)(ws);             // 16MB; reused as attn-out
  bf16* wqb = (bf16*)(ws + 16*MB);
  bf16* wkb = (bf16*)(ws + 18*MB);
  bf16* wvb = (bf16*)(ws + 20*MB);
  bf16* wob = (bf16*)(ws + 22*MB);
  bf16* Qb  = (bf16*)(ws + 24*MB);     // [b][h][s][d]
  bf16* Kb  = (bf16*)(ws + 40*MB);     // [b][h][s][d]
  bf16* Vb  = (bf16*)(ws + 56*MB);     // [b][h][d][s]
  bf16* Ab  = xb;

  k_cvt<<<MR*HID/4/256, 256, 0, stream>>>(x, xb, MR*HID/4);
  k_cvt4<<<dim3(HID*KD/4/256, 4), 256, 0, stream>>>(Wq, Wk, Wv, Wo, wqb, wkb, wvb, wob, HID*KD/4);

  k_gemm_p<0><<<dim3(MR/128, 12), 512, 0, stream>>>(xb, wqb, wkb, wvb, bq, bk, bv, Qb, Kb, Vb);

  k_attn<<<dim3(8, BB*NH), 256, 0, stream>>>(Qb, Kb, Vb, Ab);

  k_gemm_p<1><<<dim3(MR/128, 4), 512, 0, stream>>>(Ab, wob, wob, wob, bo, bo, bo, d_out, d_out, d_out);
}